// Round 8
// baseline (114.220 us; speedup 1.0000x reference)
//
#include <hip/hip_runtime.h>

#define DD 160
#define HH 160
#define WW 160
#define VOL (DD * HH * WW)   // per-batch volume = 4,096,000
#define PLANE (HH * WW)      // 25,600
#define NB 2

// pass 1a: D-sum streaming
#define CH 32                // d-centers per block
#define NDSP (DD / CH)       // 5
#define DSBLK (PLANE / 256)  // 100 hw-tiles
#define NDSUM (DSBLK * NDSP * NB)  // 1000 blocks

// pass 1b: grad
#define GCHD 20
#define GBLK (NB * 3 * (DD / GCHD) * HH * (WW / 4) / 256)   // 1200 blocks

// pass 2: WH + cc
#define HT 16
#define HS (HT + 8)          // 24 staged rows
#define LDWH 168             // LDS row stride (halves), 336B
#define WHBLK ((HH / HT) * DD * NB)   // 3200

typedef _Float16 h8 __attribute__((ext_vector_type(8)));
typedef _Float16 h4 __attribute__((ext_vector_type(4)));

// ---------------------------------------------------------------------------
// Pass 1 (merged): blocks [0, NDSUM) do the D-direction box sum of the 5
// moment fields (pure register streaming: ring of 9 raw m,f planes per
// thread-column, no LDS, no barriers); blocks [NDSUM, NDSUM+GBLK) do the
// flow L1-gradient reduction.
// ---------------------------------------------------------------------------
__global__ __launch_bounds__(256) void stream_pass(const float* __restrict__ mv,
                                                   const float* __restrict__ fx,
                                                   const float* __restrict__ fl,
                                                   _Float16* __restrict__ fields,
                                                   float* __restrict__ pg) {
    const int bx  = blockIdx.x;
    const int tid = threadIdx.x;

    if (bx < NDSUM) {
        // ---- D-sum: thread owns one (h,w) column over CH d-centers ----
        const int hwb = bx % DSBLK;
        const int rem = bx / DSBLK;
        const int dsp = rem % NDSP;
        const int b   = rem / NDSP;
        const int hw  = hwb * 256 + tid;
        const int c0  = dsp * CH;

        const float* pm = mv + (size_t)b * VOL + hw;
        const float* pf = fx + (size_t)b * VOL + hw;
        _Float16*    fb = fields + (size_t)b * 5 * VOL + hw;

        float hm[9], hf[9];
        float s0 = 0.f, s1 = 0.f, s2 = 0.f, s3 = 0.f, s4 = 0.f;

#pragma unroll
        for (int jj = 0; jj < CH + 8; ++jj) {
            const int j = c0 - 4 + jj;          // plane being added
            if (jj >= 9) {                       // subtract plane j-9 (slot holds 0 if invalid)
                float m = hm[jj % 9], f = hf[jj % 9];
                s0 -= m; s1 -= f;
                s2 -= m * m; s3 -= f * f; s4 -= m * f;
            }
            if (j >= 0 && j < DD) {
                float m = pm[(size_t)j * PLANE];
                float f = pf[(size_t)j * PLANE];
                s0 += m; s1 += f;
                s2 = fmaf(m, m, s2); s3 = fmaf(f, f, s3); s4 = fmaf(m, f, s4);
                hm[jj % 9] = m; hf[jj % 9] = f;
            } else {
                hm[jj % 9] = 0.f; hf[jj % 9] = 0.f;
            }
            if (jj >= 8) {                       // emit center dc = j - 4 = c0 + jj - 8
                const int dc = j - 4;
                _Float16* o = fb + (size_t)dc * PLANE;
                o[0 * (size_t)VOL] = (_Float16)s0;
                o[1 * (size_t)VOL] = (_Float16)s1;
                o[2 * (size_t)VOL] = (_Float16)s2;
                o[3 * (size_t)VOL] = (_Float16)s3;
                o[4 * (size_t)VOL] = (_Float16)s4;
            }
        }
        return;
    }

    // ---- grad: L1 forward diffs on flow, d-walking float4 chunks ----
    const int gid = (bx - NDSUM) * 256 + tid;    // 0..307199
    const int w4  = gid % 40;
    int t = gid / 40;
    const int h  = t % HH;  t /= HH;
    const int dc = t % (DD / GCHD); t /= (DD / GCHD);
    const int bc = t;                            // 0..5
    const int d0 = dc * GCHD;
    const int w  = w4 * 4;

    const float* base = fl + (size_t)bc * VOL;
    float acc = 0.f;
    float4 v = *(const float4*)(base + ((size_t)d0 * HH + h) * WW + w);
    for (int d = d0; d < d0 + GCHD; ++d) {
        const float* pd = base + ((size_t)d * HH + h) * WW + w;
        float4 vn = v;
        if (d < DD - 1) {
            vn = *(const float4*)(pd + PLANE);
            acc += fabsf(vn.x - v.x) + fabsf(vn.y - v.y) +
                   fabsf(vn.z - v.z) + fabsf(vn.w - v.w);
        }
        if (h < HH - 1) {
            float4 vh = *(const float4*)(pd + WW);
            acc += fabsf(vh.x - v.x) + fabsf(vh.y - v.y) +
                   fabsf(vh.z - v.z) + fabsf(vh.w - v.w);
        }
        acc += fabsf(v.y - v.x) + fabsf(v.z - v.y) + fabsf(v.w - v.z);
        if (w < WW - 4) acc += fabsf(pd[4] - v.w);
        v = vn;
    }

    for (int o = 32; o > 0; o >>= 1) acc += __shfl_down(acc, o, 64);
    __shared__ float red[4];
    int lane = tid & 63, wid = tid >> 6;
    if (lane == 0) red[wid] = acc;
    __syncthreads();
    if (tid == 0) pg[bx - NDSUM] = red[0] + red[1] + red[2] + red[3];
}

// ---------------------------------------------------------------------------
// Pass 2: W+H box sums of the 5 D-summed fields + per-voxel cc + reduction.
// Block: 512 thr, output tile 16h x 160w at one (d, b). Grid (10, 160, 2).
// Stage A (480 thr): thread (r,s) stages row r (h0-4+r), octet w0=8s: 4 h4
//   loads per field, fp32 register slide, h8 store into LDS wsum.
// Stage B (320 thr): thread (ro, oct): 45 b128 LDS reads (9 rows x 5 fields),
//   fp32 column sums, 8 cc values, accumulate. No global writes but partial.
// ---------------------------------------------------------------------------
__global__ __launch_bounds__(512, 6) void ncc_whcc(const _Float16* __restrict__ fields,
                                                   float* __restrict__ partial) {
    __shared__ _Float16 ws[5][HS][LDWH];
    __shared__ float red[8];

    const int hx  = blockIdx.x;        // 0..9
    const int d   = blockIdx.y;        // 0..159
    const int b   = blockIdx.z;        // 0..1
    const int h0  = hx * HT;
    const int tid = threadIdx.x;

    if (tid < 480) {
        const int r  = tid / 20;       // 0..23 staged row
        const int s  = tid - r * 20;   // 0..19 octet
        const int h  = h0 - 4 + r;
        const int w0 = 8 * s;
        const bool rowok = (unsigned)h < (unsigned)HH;

#pragma unroll
        for (int f = 0; f < 5; ++f) {
            float v[16];
#pragma unroll
            for (int i = 0; i < 16; ++i) v[i] = 0.f;
            if (rowok) {
                const _Float16* fr = fields + (size_t)(b * 5 + f) * VOL
                                            + ((size_t)d * HH + h) * WW;
                if (s > 0) {
                    h4 a = *(const h4*)(fr + w0 - 4);
                    v[0] = (float)a.x; v[1] = (float)a.y; v[2] = (float)a.z; v[3] = (float)a.w;
                }
                h4 a1 = *(const h4*)(fr + w0);
                v[4] = (float)a1.x; v[5] = (float)a1.y; v[6] = (float)a1.z; v[7] = (float)a1.w;
                h4 a2 = *(const h4*)(fr + w0 + 4);
                v[8] = (float)a2.x; v[9] = (float)a2.y; v[10] = (float)a2.z; v[11] = (float)a2.w;
                if (s < 19) {
                    h4 a3 = *(const h4*)(fr + w0 + 8);
                    v[12] = (float)a3.x; v[13] = (float)a3.y; v[14] = (float)a3.z; v[15] = (float)a3.w;
                }
            }
            float o[8];
            float sum = 0.f;
#pragma unroll
            for (int i = 0; i < 9; ++i) sum += v[i];
            o[0] = sum;
#pragma unroll
            for (int k = 1; k < 8; ++k) {
                sum += v[k + 8] - v[k - 1];
                o[k] = sum;
            }
            h8 pk;
#pragma unroll
            for (int j = 0; j < 8; ++j) pk[j] = (_Float16)o[j];
            *(h8*)&ws[f][r][w0] = pk;
        }
    }
    __syncthreads();

    float acc = 0.f;
    if (tid < 320) {
        const int ro  = tid / 20;      // 0..15 output row
        const int oct = tid - ro * 20; // 0..19
        const int w   = 8 * oct;

        float s0[8], s1[8], s2[8], s3[8], s4[8];
#pragma unroll
        for (int j = 0; j < 8; ++j) { s0[j]=0.f; s1[j]=0.f; s2[j]=0.f; s3[j]=0.f; s4[j]=0.f; }
#pragma unroll
        for (int t = 0; t < 9; ++t) {
            h8 v0 = *(const h8*)&ws[0][ro + t][w];
            h8 v1 = *(const h8*)&ws[1][ro + t][w];
            h8 v2 = *(const h8*)&ws[2][ro + t][w];
            h8 v3 = *(const h8*)&ws[3][ro + t][w];
            h8 v4 = *(const h8*)&ws[4][ro + t][w];
#pragma unroll
            for (int j = 0; j < 8; ++j) {
                s0[j] += (float)v0[j]; s1[j] += (float)v1[j];
                s2[j] += (float)v2[j]; s3[j] += (float)v3[j];
                s4[j] += (float)v4[j];
            }
        }
        const float inv_win = 1.0f / 729.0f;
#pragma unroll
        for (int j = 0; j < 8; ++j) {
            float cross = fmaf(-(s0[j] * s1[j]), inv_win, s4[j]);
            float pv = fmaxf(fmaf(-(s0[j] * s0[j]), inv_win, s2[j]), 0.f);
            float tv = fmaxf(fmaf(-(s1[j] * s1[j]), inv_win, s3[j]), 0.f);
            float cc = cross * cross / (pv * tv + 0.001f);
            acc += fminf(fmaxf(cc, 0.f), 1.f);
        }
    }

    for (int o = 32; o > 0; o >>= 1) acc += __shfl_down(acc, o, 64);
    int lane = tid & 63, wid = tid >> 6;
    if (lane == 0) red[wid] = acc;
    __syncthreads();
    if (tid == 0) {
        float r8 = 0.f;
#pragma unroll
        for (int i = 0; i < 8; ++i) r8 += red[i];
        partial[((size_t)b * DD + d) * (HH / HT) + hx] = r8;
    }
}

// ---------------------------------------------------------------------------
// Pass 3: final deterministic reduction of partials -> scalar loss
// ---------------------------------------------------------------------------
__global__ __launch_bounds__(256) void finalize(const float* __restrict__ pcc, int ncc,
                                                const float* __restrict__ pg, int ng,
                                                float* __restrict__ out) {
    __shared__ float red[4];
    int lane = threadIdx.x & 63, wid = threadIdx.x >> 6;

    float a = 0.f;
    for (int i = threadIdx.x; i < ncc; i += 256) a += pcc[i];
    for (int o = 32; o > 0; o >>= 1) a += __shfl_down(a, o, 64);
    if (lane == 0) red[wid] = a;
    __syncthreads();
    float asum = red[0] + red[1] + red[2] + red[3];
    __syncthreads();

    float g = 0.f;
    for (int i = threadIdx.x; i < ng; i += 256) g += pg[i];
    for (int o = 32; o > 0; o >>= 1) g += __shfl_down(g, o, 64);
    if (lane == 0) red[wid] = g;
    __syncthreads();
    float gsum = red[0] + red[1] + red[2] + red[3];

    if (threadIdx.x == 0) {
        float sim = 1.0f - asum / 8192000.0f;          // mean over (2,1,160,160,160)
        float reg = gsum / 73267200.0f;                // 3 * (2*3*159*160*160)
        out[0] = sim + reg;
    }
}

// ---------------------------------------------------------------------------
extern "C" void kernel_launch(void* const* d_in, const int* in_sizes, int n_in,
                              void* d_out, int out_size, void* d_ws, size_t ws_size,
                              hipStream_t stream) {
    const float* moved  = (const float*)d_in[0];
    const float* fixedp = (const float*)d_in[1];
    const float* flow   = (const float*)d_in[2];
    float* out = (float*)d_out;

    _Float16* fields = (_Float16*)d_ws;                   // NB*5*VOL fp16 (81.9 MB)
    float* pcc = (float*)(fields + (size_t)NB * 5 * VOL); // WHBLK floats
    float* pg  = pcc + WHBLK;                             // GBLK floats

    stream_pass<<<NDSUM + GBLK, 256, 0, stream>>>(moved, fixedp, flow, fields, pg);
    ncc_whcc<<<dim3(HH / HT, DD, NB), 512, 0, stream>>>(fields, pcc);
    finalize<<<1, 256, 0, stream>>>(pcc, WHBLK, pg, GBLK, out);
}